// Round 1
// baseline (1536.898 us; speedup 1.0000x reference)
//
#include <hip/hip_runtime.h>

#define N_NODES 50000
#define N_EDGES 800000
#define DIM     128

// ---------------------------------------------------------------------------
// Kernel 1: Q/K/V projection.  32 rows per block, 256 threads.
// thread t: col j = t&127, row-half rh = t>>7 (16 rows each), 48 accumulators.
// x tile staged in LDS (pad 132 -> distinct banks across rows; reads are
// wave-uniform broadcasts anyway).
// ---------------------------------------------------------------------------
__global__ __launch_bounds__(256) void qkv_kernel(
    const float* __restrict__ x,
    const float* __restrict__ Wq, const float* __restrict__ bq,
    const float* __restrict__ Wk, const float* __restrict__ bk,
    const float* __restrict__ Wv, const float* __restrict__ bv,
    float* __restrict__ Q, float* __restrict__ K, float* __restrict__ V)
{
    __shared__ float xs[32][132];
    const int n0 = blockIdx.x * 32;
    const int t  = threadIdx.x;

    for (int idx = t; idx < 32 * 128; idx += 256) {
        int r = idx >> 7, c = idx & 127;
        float v = 0.f;
        if (n0 + r < N_NODES) v = x[(size_t)(n0 + r) * DIM + c];
        xs[r][c] = v;
    }
    __syncthreads();

    const int j  = t & 127;
    const int rh = t >> 7;          // 0 or 1

    float accQ[16], accK[16], accV[16];
#pragma unroll
    for (int i = 0; i < 16; ++i) { accQ[i] = accK[i] = accV[i] = 0.f; }

    for (int k = 0; k < 128; ++k) {
        float wq = Wq[k * DIM + j];
        float wk = Wk[k * DIM + j];
        float wv = Wv[k * DIM + j];
#pragma unroll
        for (int i = 0; i < 16; ++i) {
            float xv = xs[rh * 16 + i][k];
            accQ[i] = fmaf(xv, wq, accQ[i]);
            accK[i] = fmaf(xv, wk, accK[i]);
            accV[i] = fmaf(xv, wv, accV[i]);
        }
    }

    const float bqv = bq[j], bkv = bk[j], bvv = bv[j];
#pragma unroll
    for (int i = 0; i < 16; ++i) {
        int r = n0 + rh * 16 + i;
        if (r < N_NODES) {
            size_t o = (size_t)r * DIM + j;
            Q[o] = accQ[i] + bqv;
            K[o] = accK[i] + bkv;
            V[o] = accV[i] + bvv;
        }
    }
}

// ---------------------------------------------------------------------------
// Kernel 2: per-edge attention + scatter.  32 lanes per edge (float4/lane).
// head h owns lanes 4h..4h+3 (floats 16h..16h+15).  4-lane shfl_xor reduce.
// ---------------------------------------------------------------------------
__global__ __launch_bounds__(256) void edge_kernel(
    const int* __restrict__ src, const int* __restrict__ dst,
    const float* __restrict__ Q, const float* __restrict__ K,
    const float* __restrict__ V,
    float* __restrict__ wV)
{
    const int e = blockIdx.x * 8 + (threadIdx.x >> 5);
    if (e >= N_EDGES) return;
    const int lane = threadIdx.x & 31;

    const int s = src[e];
    const int d = dst[e];

    float4 kv = ((const float4*)(K + (size_t)s * DIM))[lane];
    float4 qv = ((const float4*)(Q + (size_t)d * DIM))[lane];
    float dot = kv.x * qv.x + kv.y * qv.y + kv.z * qv.z + kv.w * qv.w;
    dot += __shfl_xor(dot, 1);
    dot += __shfl_xor(dot, 2);          // all 4 lanes of the head hold the dot

    float sc = dot * 0.25f;             // 1/sqrt(16)
    sc = fminf(fmaxf(sc, -5.f), 5.f);
    sc = expf(sc);

    float4 vv = ((const float4*)(V + (size_t)s * DIM))[lane];
    float* o = wV + (size_t)d * DIM + lane * 4;
    atomicAdd(o + 0, vv.x * sc);
    atomicAdd(o + 1, vv.y * sc);
    atomicAdd(o + 2, vv.z * sc);
    atomicAdd(o + 3, vv.w * sc);
}

// ---------------------------------------------------------------------------
// Kernel 3: h = LN1(x + wV), u = LN2(h).  One 64-lane wave per row, 2 elems
// per lane, shfl_xor tree reductions.
// ---------------------------------------------------------------------------
__global__ __launch_bounds__(256) void ln_kernel(
    const float* __restrict__ x, const float* __restrict__ wV,
    const float* __restrict__ g1, const float* __restrict__ b1,
    const float* __restrict__ g2, const float* __restrict__ b2,
    float* __restrict__ h, float* __restrict__ u)
{
    const int row = blockIdx.x * 4 + (threadIdx.x >> 6);
    if (row >= N_NODES) return;
    const int lane = threadIdx.x & 63;

    float2 xv = ((const float2*)(x  + (size_t)row * DIM))[lane];
    float2 wv = ((const float2*)(wV + (size_t)row * DIM))[lane];
    float a0 = xv.x + wv.x;
    float a1 = xv.y + wv.y;

    float sum = a0 + a1;
#pragma unroll
    for (int m = 1; m < 64; m <<= 1) sum += __shfl_xor(sum, m);
    float mean = sum * (1.f / 128.f);

    float d0 = a0 - mean, d1 = a1 - mean;
    float vs = d0 * d0 + d1 * d1;
#pragma unroll
    for (int m = 1; m < 64; m <<= 1) vs += __shfl_xor(vs, m);
    float rstd = rsqrtf(vs * (1.f / 128.f) + 1e-5f);

    float2 g1v = ((const float2*)g1)[lane];
    float2 b1v = ((const float2*)b1)[lane];
    float h0 = d0 * rstd * g1v.x + b1v.x;
    float h1 = d1 * rstd * g1v.y + b1v.y;
    ((float2*)(h + (size_t)row * DIM))[lane] = make_float2(h0, h1);

    // LN2 over h
    float sum2 = h0 + h1;
#pragma unroll
    for (int m = 1; m < 64; m <<= 1) sum2 += __shfl_xor(sum2, m);
    float mean2 = sum2 * (1.f / 128.f);

    float e0 = h0 - mean2, e1 = h1 - mean2;
    float vs2 = e0 * e0 + e1 * e1;
#pragma unroll
    for (int m = 1; m < 64; m <<= 1) vs2 += __shfl_xor(vs2, m);
    float rstd2 = rsqrtf(vs2 * (1.f / 128.f) + 1e-5f);

    float2 g2v = ((const float2*)g2)[lane];
    float2 b2v = ((const float2*)b2)[lane];
    float u0 = e0 * rstd2 * g2v.x + b2v.x;
    float u1 = e1 * rstd2 * g2v.y + b2v.y;
    ((float2*)(u + (size_t)row * DIM))[lane] = make_float2(u0, u1);
}

// ---------------------------------------------------------------------------
// Kernel 4: out = h + relu(u @ Wo + bo).  Same tiling as kernel 1.
// h lives in d_out already (elementwise in-place is safe: one thread per elem).
// ---------------------------------------------------------------------------
__global__ __launch_bounds__(256) void out_kernel(
    const float* __restrict__ u,
    const float* __restrict__ Wo, const float* __restrict__ bo,
    float* __restrict__ out /* holds h on entry */)
{
    __shared__ float us[32][132];
    const int n0 = blockIdx.x * 32;
    const int t  = threadIdx.x;

    for (int idx = t; idx < 32 * 128; idx += 256) {
        int r = idx >> 7, c = idx & 127;
        float v = 0.f;
        if (n0 + r < N_NODES) v = u[(size_t)(n0 + r) * DIM + c];
        us[r][c] = v;
    }
    __syncthreads();

    const int j  = t & 127;
    const int rh = t >> 7;

    float acc[16];
#pragma unroll
    for (int i = 0; i < 16; ++i) acc[i] = 0.f;

    for (int k = 0; k < 128; ++k) {
        float wo = Wo[k * DIM + j];
#pragma unroll
        for (int i = 0; i < 16; ++i)
            acc[i] = fmaf(us[rh * 16 + i][k], wo, acc[i]);
    }

    const float bov = bo[j];
#pragma unroll
    for (int i = 0; i < 16; ++i) {
        int r = n0 + rh * 16 + i;
        if (r < N_NODES) {
            size_t o = (size_t)r * DIM + j;
            out[o] = out[o] + fmaxf(acc[i] + bov, 0.f);
        }
    }
}

// ---------------------------------------------------------------------------
extern "C" void kernel_launch(void* const* d_in, const int* in_sizes, int n_in,
                              void* d_out, int out_size, void* d_ws, size_t ws_size,
                              hipStream_t stream)
{
    const float* x    = (const float*)d_in[0];
    const int*   src  = (const int*)  d_in[1];
    const int*   dst  = (const int*)  d_in[2];
    const float* Wq   = (const float*)d_in[3];
    const float* bq   = (const float*)d_in[4];
    const float* Wk   = (const float*)d_in[5];
    const float* bk   = (const float*)d_in[6];
    const float* Wv   = (const float*)d_in[7];
    const float* bv   = (const float*)d_in[8];
    const float* Wo   = (const float*)d_in[9];
    const float* bo   = (const float*)d_in[10];
    const float* ln1g = (const float*)d_in[11];
    const float* ln1b = (const float*)d_in[12];
    const float* ln2g = (const float*)d_in[13];
    const float* ln2b = (const float*)d_in[14];

    float* out = (float*)d_out;              // will hold h, then final output
    float* ws  = (float*)d_ws;

    const size_t NM = (size_t)N_NODES * DIM; // 6.4M floats
    float* Q  = ws;
    float* K  = ws + NM;
    float* V  = ws + 2 * NM;
    float* wV = ws + 3 * NM;
    float* u  = ws + 4 * NM;                 // 5*NM floats = 128 MB total

    hipMemsetAsync(wV, 0, NM * sizeof(float), stream);

    qkv_kernel<<<(N_NODES + 31) / 32, 256, 0, stream>>>(
        x, Wq, bq, Wk, bk, Wv, bv, Q, K, V);

    edge_kernel<<<N_EDGES / 8, 256, 0, stream>>>(src, dst, Q, K, V, wV);

    ln_kernel<<<(N_NODES + 3) / 4, 256, 0, stream>>>(
        x, wV, ln1g, ln1b, ln2g, ln2b, out, u);

    out_kernel<<<(N_NODES + 31) / 32, 256, 0, stream>>>(u, Wo, bo, out);
}

// Round 2
// 323.596 us; speedup vs baseline: 4.7494x; 4.7494x over previous
//
#include <hip/hip_runtime.h>

#define N_NODES 50000
#define N_EDGES 800000
#define DIM     128
#define CAP     96          // per-dst bucket capacity (avg degree 16, Poisson tail << 96)

// ---------------------------------------------------------------------------
// Kernel 1: Q/K/V projection.  32 rows per block, 256 threads.
// ---------------------------------------------------------------------------
__global__ __launch_bounds__(256) void qkv_kernel(
    const float* __restrict__ x,
    const float* __restrict__ Wq, const float* __restrict__ bq,
    const float* __restrict__ Wk, const float* __restrict__ bk,
    const float* __restrict__ Wv, const float* __restrict__ bv,
    float* __restrict__ Q, float* __restrict__ K, float* __restrict__ V)
{
    __shared__ float xs[32][132];
    const int n0 = blockIdx.x * 32;
    const int t  = threadIdx.x;

    for (int idx = t; idx < 32 * 128; idx += 256) {
        int r = idx >> 7, c = idx & 127;
        float v = 0.f;
        if (n0 + r < N_NODES) v = x[(size_t)(n0 + r) * DIM + c];
        xs[r][c] = v;
    }
    __syncthreads();

    const int j  = t & 127;
    const int rh = t >> 7;          // 0 or 1

    float accQ[16], accK[16], accV[16];
#pragma unroll
    for (int i = 0; i < 16; ++i) { accQ[i] = accK[i] = accV[i] = 0.f; }

    for (int k = 0; k < 128; ++k) {
        float wq = Wq[k * DIM + j];
        float wk = Wk[k * DIM + j];
        float wv = Wv[k * DIM + j];
#pragma unroll
        for (int i = 0; i < 16; ++i) {
            float xv = xs[rh * 16 + i][k];
            accQ[i] = fmaf(xv, wq, accQ[i]);
            accK[i] = fmaf(xv, wk, accK[i]);
            accV[i] = fmaf(xv, wv, accV[i]);
        }
    }

    const float bqv = bq[j], bkv = bk[j], bvv = bv[j];
#pragma unroll
    for (int i = 0; i < 16; ++i) {
        int r = n0 + rh * 16 + i;
        if (r < N_NODES) {
            size_t o = (size_t)r * DIM + j;
            Q[o] = accQ[i] + bqv;
            K[o] = accK[i] + bkv;
            V[o] = accV[i] + bvv;
        }
    }
}

// ---------------------------------------------------------------------------
// Kernel 2: invert edge list into per-dst buckets (src ids).
// counts must be zeroed before launch.
// ---------------------------------------------------------------------------
__global__ __launch_bounds__(256) void fill_kernel(
    const int* __restrict__ src, const int* __restrict__ dst,
    int* __restrict__ counts, int* __restrict__ bucket)
{
    const int e = blockIdx.x * 256 + threadIdx.x;
    if (e >= N_EDGES) return;
    const int s = src[e];
    const int d = dst[e];
    const int pos = atomicAdd(&counts[d], 1);
    if (pos < CAP) bucket[(size_t)d * CAP + pos] = s;
}

// ---------------------------------------------------------------------------
// Kernel 3: per-dst gather + softmax-weighted sum + LN1 + LN2, fused.
// 32 lanes per node; lane owns floats 4l..4l+3 (head = lane>>2).
// ---------------------------------------------------------------------------
__global__ __launch_bounds__(256) void gather_ln_kernel(
    const float* __restrict__ x,
    const float* __restrict__ Q, const float* __restrict__ K,
    const float* __restrict__ V,
    const int* __restrict__ counts, const int* __restrict__ bucket,
    const float* __restrict__ g1, const float* __restrict__ b1,
    const float* __restrict__ g2, const float* __restrict__ b2,
    float* __restrict__ h, float* __restrict__ u)
{
    const int gid  = blockIdx.x * 256 + threadIdx.x;
    const int node = gid >> 5;
    if (node >= N_NODES) return;
    const int lane = threadIdx.x & 31;   // within the 32-lane group

    const float4* Q4 = (const float4*)Q;
    const float4* K4 = (const float4*)K;
    const float4* V4 = (const float4*)V;

    const float4 q4 = Q4[(size_t)node * 32 + lane];

    int cnt = counts[node];
    if (cnt > CAP) cnt = CAP;
    const size_t base = (size_t)node * CAP;

    float4 acc = make_float4(0.f, 0.f, 0.f, 0.f);
    for (int i = 0; i < cnt; ++i) {
        const int s = bucket[base + i];
        const float4 k4 = K4[(size_t)s * 32 + lane];
        const float4 v4 = V4[(size_t)s * 32 + lane];
        float dot = k4.x * q4.x + k4.y * q4.y + k4.z * q4.z + k4.w * q4.w;
        dot += __shfl_xor(dot, 1);
        dot += __shfl_xor(dot, 2);       // head-wide dot (4 lanes)
        float sc = dot * 0.25f;          // 1/sqrt(16)
        sc = fminf(fmaxf(sc, -5.f), 5.f);
        sc = expf(sc);
        acc.x = fmaf(v4.x, sc, acc.x);
        acc.y = fmaf(v4.y, sc, acc.y);
        acc.z = fmaf(v4.z, sc, acc.z);
        acc.w = fmaf(v4.w, sc, acc.w);
    }

    // a = x + wV
    const float4 xv = ((const float4*)x)[(size_t)node * 32 + lane];
    float a0 = xv.x + acc.x, a1 = xv.y + acc.y;
    float a2 = xv.z + acc.z, a3 = xv.w + acc.w;

    // ---- LN1 across the 32-lane group (128 elems) ----
    float sum = a0 + a1 + a2 + a3;
#pragma unroll
    for (int m = 1; m < 32; m <<= 1) sum += __shfl_xor(sum, m);
    float mean = sum * (1.f / 128.f);
    float d0 = a0 - mean, d1 = a1 - mean, d2 = a2 - mean, d3 = a3 - mean;
    float vs = d0 * d0 + d1 * d1 + d2 * d2 + d3 * d3;
#pragma unroll
    for (int m = 1; m < 32; m <<= 1) vs += __shfl_xor(vs, m);
    float rstd = rsqrtf(vs * (1.f / 128.f) + 1e-5f);

    const float4 g1v = ((const float4*)g1)[lane];
    const float4 b1v = ((const float4*)b1)[lane];
    float h0 = d0 * rstd * g1v.x + b1v.x;
    float h1 = d1 * rstd * g1v.y + b1v.y;
    float h2 = d2 * rstd * g1v.z + b1v.z;
    float h3 = d3 * rstd * g1v.w + b1v.w;
    ((float4*)h)[(size_t)node * 32 + lane] = make_float4(h0, h1, h2, h3);

    // ---- LN2 over h ----
    float sum2 = h0 + h1 + h2 + h3;
#pragma unroll
    for (int m = 1; m < 32; m <<= 1) sum2 += __shfl_xor(sum2, m);
    float mean2 = sum2 * (1.f / 128.f);
    float e0 = h0 - mean2, e1 = h1 - mean2, e2 = h2 - mean2, e3 = h3 - mean2;
    float vs2 = e0 * e0 + e1 * e1 + e2 * e2 + e3 * e3;
#pragma unroll
    for (int m = 1; m < 32; m <<= 1) vs2 += __shfl_xor(vs2, m);
    float rstd2 = rsqrtf(vs2 * (1.f / 128.f) + 1e-5f);

    const float4 g2v = ((const float4*)g2)[lane];
    const float4 b2v = ((const float4*)b2)[lane];
    ((float4*)u)[(size_t)node * 32 + lane] = make_float4(
        e0 * rstd2 * g2v.x + b2v.x,
        e1 * rstd2 * g2v.y + b2v.y,
        e2 * rstd2 * g2v.z + b2v.z,
        e3 * rstd2 * g2v.w + b2v.w);
}

// ---------------------------------------------------------------------------
// Kernel 4: out = h + relu(u @ Wo + bo).
// ---------------------------------------------------------------------------
__global__ __launch_bounds__(256) void out_kernel(
    const float* __restrict__ u,
    const float* __restrict__ Wo, const float* __restrict__ bo,
    float* __restrict__ out /* holds h on entry */)
{
    __shared__ float us[32][132];
    const int n0 = blockIdx.x * 32;
    const int t  = threadIdx.x;

    for (int idx = t; idx < 32 * 128; idx += 256) {
        int r = idx >> 7, c = idx & 127;
        float v = 0.f;
        if (n0 + r < N_NODES) v = u[(size_t)(n0 + r) * DIM + c];
        us[r][c] = v;
    }
    __syncthreads();

    const int j  = t & 127;
    const int rh = t >> 7;

    float acc[16];
#pragma unroll
    for (int i = 0; i < 16; ++i) acc[i] = 0.f;

    for (int k = 0; k < 128; ++k) {
        float wo = Wo[k * DIM + j];
#pragma unroll
        for (int i = 0; i < 16; ++i)
            acc[i] = fmaf(us[rh * 16 + i][k], wo, acc[i]);
    }

    const float bov = bo[j];
#pragma unroll
    for (int i = 0; i < 16; ++i) {
        int r = n0 + rh * 16 + i;
        if (r < N_NODES) {
            size_t o = (size_t)r * DIM + j;
            out[o] = out[o] + fmaxf(acc[i] + bov, 0.f);
        }
    }
}

// ---------------------------------------------------------------------------
extern "C" void kernel_launch(void* const* d_in, const int* in_sizes, int n_in,
                              void* d_out, int out_size, void* d_ws, size_t ws_size,
                              hipStream_t stream)
{
    const float* x    = (const float*)d_in[0];
    const int*   src  = (const int*)  d_in[1];
    const int*   dst  = (const int*)  d_in[2];
    const float* Wq   = (const float*)d_in[3];
    const float* bq   = (const float*)d_in[4];
    const float* Wk   = (const float*)d_in[5];
    const float* bk   = (const float*)d_in[6];
    const float* Wv   = (const float*)d_in[7];
    const float* bv   = (const float*)d_in[8];
    const float* Wo   = (const float*)d_in[9];
    const float* bo   = (const float*)d_in[10];
    const float* ln1g = (const float*)d_in[11];
    const float* ln1b = (const float*)d_in[12];
    const float* ln2g = (const float*)d_in[13];
    const float* ln2b = (const float*)d_in[14];

    float* out = (float*)d_out;              // will hold h, then final output
    float* ws  = (float*)d_ws;

    const size_t NM = (size_t)N_NODES * DIM; // 6.4M floats
    float* Q      = ws;
    float* K      = ws + NM;
    float* V      = ws + 2 * NM;
    float* u      = ws + 3 * NM;
    int*   counts = (int*)(ws + 4 * NM);
    int*   bucket = counts + N_NODES;        // 50000*96 ints = 19.2 MB

    hipMemsetAsync(counts, 0, N_NODES * sizeof(int), stream);

    qkv_kernel<<<(N_NODES + 31) / 32, 256, 0, stream>>>(
        x, Wq, bq, Wk, bk, Wv, bv, Q, K, V);

    fill_kernel<<<(N_EDGES + 255) / 256, 256, 0, stream>>>(
        src, dst, counts, bucket);

    gather_ln_kernel<<<(N_NODES * 32 + 255) / 256, 256, 0, stream>>>(
        x, Q, K, V, counts, bucket, ln1g, ln1b, ln2g, ln2b, out, u);

    out_kernel<<<(N_NODES + 31) / 32, 256, 0, stream>>>(u, Wo, bo, out);
}

// Round 3
// 262.874 us; speedup vs baseline: 5.8465x; 1.2310x over previous
//
#include <hip/hip_runtime.h>
#include <hip/hip_bf16.h>

#define N_NODES 50000
#define N_EDGES 800000
#define DIM     128
#define CAP     96          // per-dst bucket capacity (max degree ~40 for this graph)

// ---------------------------------------------------------------------------
// bf16 helpers (bit-level, no per-element library calls in hot loop)
// ---------------------------------------------------------------------------
__device__ __forceinline__ float bfhi(unsigned int u) {   // high ushort -> float
    union { unsigned int u; float f; } c; c.u = u & 0xffff0000u; return c.f;
}
__device__ __forceinline__ float bflo(unsigned int u) {   // low ushort -> float
    union { unsigned int u; float f; } c; c.u = u << 16; return c.f;
}
__device__ __forceinline__ void unpack8(uint4 w, float* f) {
    f[0] = bflo(w.x); f[1] = bfhi(w.x);
    f[2] = bflo(w.y); f[3] = bfhi(w.y);
    f[4] = bflo(w.z); f[5] = bfhi(w.z);
    f[6] = bflo(w.w); f[7] = bfhi(w.w);
}

// ---------------------------------------------------------------------------
// Kernel 1: Q/K/V projection (fp32 compute, bf16 outputs).
// 32 rows per block, 256 threads.
// ---------------------------------------------------------------------------
__global__ __launch_bounds__(256) void qkv_kernel(
    const float* __restrict__ x,
    const float* __restrict__ Wq, const float* __restrict__ bq,
    const float* __restrict__ Wk, const float* __restrict__ bk,
    const float* __restrict__ Wv, const float* __restrict__ bv,
    __hip_bfloat16* __restrict__ Q, __hip_bfloat16* __restrict__ K,
    __hip_bfloat16* __restrict__ V)
{
    __shared__ float xs[32][132];
    const int n0 = blockIdx.x * 32;
    const int t  = threadIdx.x;

    for (int idx = t; idx < 32 * 128; idx += 256) {
        int r = idx >> 7, c = idx & 127;
        float v = 0.f;
        if (n0 + r < N_NODES) v = x[(size_t)(n0 + r) * DIM + c];
        xs[r][c] = v;
    }
    __syncthreads();

    const int j  = t & 127;
    const int rh = t >> 7;          // 0 or 1

    float accQ[16], accK[16], accV[16];
#pragma unroll
    for (int i = 0; i < 16; ++i) { accQ[i] = accK[i] = accV[i] = 0.f; }

    for (int k = 0; k < 128; ++k) {
        float wq = Wq[k * DIM + j];
        float wk = Wk[k * DIM + j];
        float wv = Wv[k * DIM + j];
#pragma unroll
        for (int i = 0; i < 16; ++i) {
            float xv = xs[rh * 16 + i][k];
            accQ[i] = fmaf(xv, wq, accQ[i]);
            accK[i] = fmaf(xv, wk, accK[i]);
            accV[i] = fmaf(xv, wv, accV[i]);
        }
    }

    const float bqv = bq[j], bkv = bk[j], bvv = bv[j];
#pragma unroll
    for (int i = 0; i < 16; ++i) {
        int r = n0 + rh * 16 + i;
        if (r < N_NODES) {
            size_t o = (size_t)r * DIM + j;
            Q[o] = __float2bfloat16(accQ[i] + bqv);
            K[o] = __float2bfloat16(accK[i] + bkv);
            V[o] = __float2bfloat16(accV[i] + bvv);
        }
    }
}

// ---------------------------------------------------------------------------
// Kernel 2: invert edge list into per-dst buckets (src ids).
// ---------------------------------------------------------------------------
__global__ __launch_bounds__(256) void fill_kernel(
    const int* __restrict__ src, const int* __restrict__ dst,
    int* __restrict__ counts, int* __restrict__ bucket)
{
    const int e = blockIdx.x * 256 + threadIdx.x;
    if (e >= N_EDGES) return;
    const int s = src[e];
    const int d = dst[e];
    const int pos = atomicAdd(&counts[d], 1);
    if (pos < CAP) bucket[(size_t)d * CAP + pos] = s;
}

// ---------------------------------------------------------------------------
// Kernel 3: per-dst gather + weighted sum + LN1 + LN2, fused.
// 16 lanes per node; lane owns elems 8l..8l+7 (one uint4 of bf16).
// head = lane>>1; dot reduce across lane pair via shfl_xor(.,1).
// ---------------------------------------------------------------------------
__device__ __forceinline__ void edge_accum(uint4 kw, uint4 vw,
                                           const float* q, float* acc)
{
    float kf[8];
    unpack8(kw, kf);
    float dot = q[0]*kf[0] + q[1]*kf[1] + q[2]*kf[2] + q[3]*kf[3]
              + q[4]*kf[4] + q[5]*kf[5] + q[6]*kf[6] + q[7]*kf[7];
    dot += __shfl_xor(dot, 1);          // head-wide dot (2 lanes x 8)
    float sc = dot * 0.25f;             // 1/sqrt(16)
    sc = fminf(fmaxf(sc, -5.f), 5.f);
    sc = __expf(sc);
    float vf[8];
    unpack8(vw, vf);
#pragma unroll
    for (int j = 0; j < 8; ++j) acc[j] = fmaf(vf[j], sc, acc[j]);
}

__global__ __launch_bounds__(256) void gather_ln_kernel(
    const float* __restrict__ x,
    const __hip_bfloat16* __restrict__ Qb, const __hip_bfloat16* __restrict__ Kb,
    const __hip_bfloat16* __restrict__ Vb,
    const int* __restrict__ counts, const int* __restrict__ bucket,
    const float* __restrict__ g1, const float* __restrict__ b1,
    const float* __restrict__ g2, const float* __restrict__ b2,
    float* __restrict__ h, float* __restrict__ u)
{
    const int gid  = blockIdx.x * 256 + threadIdx.x;
    const int node = gid >> 4;
    if (node >= N_NODES) return;
    const int lane = threadIdx.x & 15;   // 16-lane group

    const uint4* Q4 = (const uint4*)Qb;
    const uint4* K4 = (const uint4*)Kb;
    const uint4* V4 = (const uint4*)Vb;

    float q[8];
    unpack8(Q4[(size_t)node * 16 + lane], q);

    int cnt = counts[node];
    if (cnt > CAP) cnt = CAP;
    const size_t base = (size_t)node * CAP;

    float acc[8];
#pragma unroll
    for (int j = 0; j < 8; ++j) acc[j] = 0.f;

    int i = 0;
    for (; i + 2 <= cnt; i += 2) {
        const int s0 = bucket[base + i];
        const int s1 = bucket[base + i + 1];
        const uint4 kw0 = K4[(size_t)s0 * 16 + lane];
        const uint4 vw0 = V4[(size_t)s0 * 16 + lane];
        const uint4 kw1 = K4[(size_t)s1 * 16 + lane];
        const uint4 vw1 = V4[(size_t)s1 * 16 + lane];
        edge_accum(kw0, vw0, q, acc);
        edge_accum(kw1, vw1, q, acc);
    }
    if (i < cnt) {
        const int s0 = bucket[base + i];
        const uint4 kw0 = K4[(size_t)s0 * 16 + lane];
        const uint4 vw0 = V4[(size_t)s0 * 16 + lane];
        edge_accum(kw0, vw0, q, acc);
    }

    // a = x + wV  (lane owns elems 8l..8l+7 -> two float4 loads)
    const float4* x4 = (const float4*)(x + (size_t)node * DIM);
    float4 xa = x4[lane * 2], xb = x4[lane * 2 + 1];
    float a[8] = { xa.x + acc[0], xa.y + acc[1], xa.z + acc[2], xa.w + acc[3],
                   xb.x + acc[4], xb.y + acc[5], xb.z + acc[6], xb.w + acc[7] };

    // ---- LN1 across 16-lane group (128 elems) ----
    float sum = 0.f;
#pragma unroll
    for (int j = 0; j < 8; ++j) sum += a[j];
#pragma unroll
    for (int m = 1; m < 16; m <<= 1) sum += __shfl_xor(sum, m);
    float mean = sum * (1.f / 128.f);
    float vs = 0.f;
#pragma unroll
    for (int j = 0; j < 8; ++j) { a[j] -= mean; vs += a[j] * a[j]; }
#pragma unroll
    for (int m = 1; m < 16; m <<= 1) vs += __shfl_xor(vs, m);
    float rstd = rsqrtf(vs * (1.f / 128.f) + 1e-5f);

    const float4 g1a = ((const float4*)g1)[lane * 2], g1b = ((const float4*)g1)[lane * 2 + 1];
    const float4 b1a = ((const float4*)b1)[lane * 2], b1b = ((const float4*)b1)[lane * 2 + 1];
    float hv[8];
    hv[0] = a[0] * rstd * g1a.x + b1a.x;  hv[1] = a[1] * rstd * g1a.y + b1a.y;
    hv[2] = a[2] * rstd * g1a.z + b1a.z;  hv[3] = a[3] * rstd * g1a.w + b1a.w;
    hv[4] = a[4] * rstd * g1b.x + b1b.x;  hv[5] = a[5] * rstd * g1b.y + b1b.y;
    hv[6] = a[6] * rstd * g1b.z + b1b.z;  hv[7] = a[7] * rstd * g1b.w + b1b.w;

    float4* h4 = (float4*)(h + (size_t)node * DIM);
    h4[lane * 2]     = make_float4(hv[0], hv[1], hv[2], hv[3]);
    h4[lane * 2 + 1] = make_float4(hv[4], hv[5], hv[6], hv[7]);

    // ---- LN2 over h ----
    float sum2 = 0.f;
#pragma unroll
    for (int j = 0; j < 8; ++j) sum2 += hv[j];
#pragma unroll
    for (int m = 1; m < 16; m <<= 1) sum2 += __shfl_xor(sum2, m);
    float mean2 = sum2 * (1.f / 128.f);
    float vs2 = 0.f;
#pragma unroll
    for (int j = 0; j < 8; ++j) { hv[j] -= mean2; vs2 += hv[j] * hv[j]; }
#pragma unroll
    for (int m = 1; m < 16; m <<= 1) vs2 += __shfl_xor(vs2, m);
    float rstd2 = rsqrtf(vs2 * (1.f / 128.f) + 1e-5f);

    const float4 g2a = ((const float4*)g2)[lane * 2], g2b = ((const float4*)g2)[lane * 2 + 1];
    const float4 b2a = ((const float4*)b2)[lane * 2], b2b = ((const float4*)b2)[lane * 2 + 1];
    float4* u4 = (float4*)(u + (size_t)node * DIM);
    u4[lane * 2] = make_float4(
        hv[0] * rstd2 * g2a.x + b2a.x, hv[1] * rstd2 * g2a.y + b2a.y,
        hv[2] * rstd2 * g2a.z + b2a.z, hv[3] * rstd2 * g2a.w + b2a.w);
    u4[lane * 2 + 1] = make_float4(
        hv[4] * rstd2 * g2b.x + b2b.x, hv[5] * rstd2 * g2b.y + b2b.y,
        hv[6] * rstd2 * g2b.z + b2b.z, hv[7] * rstd2 * g2b.w + b2b.w);
}

// ---------------------------------------------------------------------------
// Kernel 4: out = h + relu(u @ Wo + bo).
// ---------------------------------------------------------------------------
__global__ __launch_bounds__(256) void out_kernel(
    const float* __restrict__ u,
    const float* __restrict__ Wo, const float* __restrict__ bo,
    float* __restrict__ out /* holds h on entry */)
{
    __shared__ float us[32][132];
    const int n0 = blockIdx.x * 32;
    const int t  = threadIdx.x;

    for (int idx = t; idx < 32 * 128; idx += 256) {
        int r = idx >> 7, c = idx & 127;
        float v = 0.f;
        if (n0 + r < N_NODES) v = u[(size_t)(n0 + r) * DIM + c];
        us[r][c] = v;
    }
    __syncthreads();

    const int j  = t & 127;
    const int rh = t >> 7;

    float acc[16];
#pragma unroll
    for (int i = 0; i < 16; ++i) acc[i] = 0.f;

    for (int k = 0; k < 128; ++k) {
        float wo = Wo[k * DIM + j];
#pragma unroll
        for (int i = 0; i < 16; ++i)
            acc[i] = fmaf(us[rh * 16 + i][k], wo, acc[i]);
    }

    const float bov = bo[j];
#pragma unroll
    for (int i = 0; i < 16; ++i) {
        int r = n0 + rh * 16 + i;
        if (r < N_NODES) {
            size_t o = (size_t)r * DIM + j;
            out[o] = out[o] + fmaxf(acc[i] + bov, 0.f);
        }
    }
}

// ---------------------------------------------------------------------------
extern "C" void kernel_launch(void* const* d_in, const int* in_sizes, int n_in,
                              void* d_out, int out_size, void* d_ws, size_t ws_size,
                              hipStream_t stream)
{
    const float* x    = (const float*)d_in[0];
    const int*   src  = (const int*)  d_in[1];
    const int*   dst  = (const int*)  d_in[2];
    const float* Wq   = (const float*)d_in[3];
    const float* bq   = (const float*)d_in[4];
    const float* Wk   = (const float*)d_in[5];
    const float* bk   = (const float*)d_in[6];
    const float* Wv   = (const float*)d_in[7];
    const float* bv   = (const float*)d_in[8];
    const float* Wo   = (const float*)d_in[9];
    const float* bo   = (const float*)d_in[10];
    const float* ln1g = (const float*)d_in[11];
    const float* ln1b = (const float*)d_in[12];
    const float* ln2g = (const float*)d_in[13];
    const float* ln2b = (const float*)d_in[14];

    float* out = (float*)d_out;              // will hold h, then final output
    float* ws  = (float*)d_ws;

    const size_t NM = (size_t)N_NODES * DIM; // 6.4M elems
    __hip_bfloat16* Qb = (__hip_bfloat16*)ws;            // NM bf16 = 12.8 MB
    __hip_bfloat16* Kb = Qb + NM;
    __hip_bfloat16* Vb = Kb + NM;
    float* u      = (float*)(Vb + NM);                   // NM fp32
    int*   counts = (int*)(u + NM);
    int*   bucket = counts + N_NODES;                    // 19.2 MB

    hipMemsetAsync(counts, 0, N_NODES * sizeof(int), stream);

    qkv_kernel<<<(N_NODES + 31) / 32, 256, 0, stream>>>(
        x, Wq, bq, Wk, bk, Wv, bv, Qb, Kb, Vb);

    fill_kernel<<<(N_EDGES + 255) / 256, 256, 0, stream>>>(
        src, dst, counts, bucket);

    gather_ln_kernel<<<(N_NODES * 16 + 255) / 256, 256, 0, stream>>>(
        x, Qb, Kb, Vb, counts, bucket, ln1g, ln1b, ln2g, ln2b, out, u);

    out_kernel<<<(N_NODES + 31) / 32, 256, 0, stream>>>(u, Wo, bo, out);
}

// Round 4
// 200.913 us; speedup vs baseline: 7.6496x; 1.3084x over previous
//
#include <hip/hip_runtime.h>
#include <hip/hip_bf16.h>

#define N_NODES 50000
#define N_EDGES 800000
#define DIM     128
#define CAP     96          // per-dst bucket capacity (max degree ~40 for this graph)

typedef __attribute__((ext_vector_type(8))) short bf16x8;
typedef __attribute__((ext_vector_type(4))) float f32x4;

// ---------------------------------------------------------------------------
// bf16 helpers
// ---------------------------------------------------------------------------
__device__ __forceinline__ unsigned short f2bf(float f) {   // RNE
    union { float f; unsigned u; } c; c.f = f;
    unsigned r = c.u + 0x7fffu + ((c.u >> 16) & 1u);
    return (unsigned short)(r >> 16);
}
__device__ __forceinline__ float bfhi(unsigned int u) {
    union { unsigned int u; float f; } c; c.u = u & 0xffff0000u; return c.f;
}
__device__ __forceinline__ float bflo(unsigned int u) {
    union { unsigned int u; float f; } c; c.u = u << 16; return c.f;
}
__device__ __forceinline__ void unpack8(uint4 w, float* f) {
    f[0] = bflo(w.x); f[1] = bfhi(w.x);
    f[2] = bflo(w.y); f[3] = bfhi(w.y);
    f[4] = bflo(w.z); f[5] = bfhi(w.z);
    f[6] = bflo(w.w); f[7] = bfhi(w.w);
}

// ---------------------------------------------------------------------------
// Kernel 0: transpose weights to [n][k] bf16, concat qkv bias.
// ---------------------------------------------------------------------------
__global__ __launch_bounds__(256) void prep_kernel(
    const float* __restrict__ Wq, const float* __restrict__ Wk,
    const float* __restrict__ Wv, const float* __restrict__ Wo,
    const float* __restrict__ bq, const float* __restrict__ bk,
    const float* __restrict__ bv,
    unsigned short* __restrict__ WT, unsigned short* __restrict__ WoT,
    float* __restrict__ bqkv)
{
    const int t = blockIdx.x * 256 + threadIdx.x;
    if (t < 384 * 128) {
        int j = t >> 7, k = t & 127;
        int which = j >> 7, jj = j & 127;
        const float* W = which == 0 ? Wq : which == 1 ? Wk : Wv;
        WT[t] = f2bf(W[k * 128 + jj]);
    } else if (t < 384 * 128 + 128 * 128) {
        int t2 = t - 384 * 128;
        int j = t2 >> 7, k = t2 & 127;
        WoT[t2] = f2bf(Wo[k * 128 + j]);
    } else if (t < 384 * 128 + 128 * 128 + 384) {
        int j = t - (384 * 128 + 128 * 128);
        bqkv[j] = j < 128 ? bq[j] : j < 256 ? bk[j - 128] : bv[j - 256];
    }
}

// ---------------------------------------------------------------------------
// Kernel 1: QKV projection via MFMA.  Block = 4 waves, 32 rows.
// Wave w computes cols [96w, 96w+96) over the block's 32 rows (2 rowgroups).
// A = x (fp32 -> bf16 inline), B = WT[n][k] bf16, fp32 accumulate.
// ---------------------------------------------------------------------------
__global__ __launch_bounds__(256) void qkv_mfma(
    const float* __restrict__ x, const unsigned short* __restrict__ WT,
    const float* __restrict__ bqkv,
    unsigned short* __restrict__ Q, unsigned short* __restrict__ K,
    unsigned short* __restrict__ V)
{
    const int w   = threadIdx.x >> 6;
    const int l   = threadIdx.x & 63;
    const int l15 = l & 15;
    const int lk  = l >> 4;
    const int n0  = blockIdx.x * 32;

    f32x4 acc[6][2];
#pragma unroll
    for (int t = 0; t < 6; ++t)
#pragma unroll
        for (int rg = 0; rg < 2; ++rg) acc[t][rg] = (f32x4){0.f, 0.f, 0.f, 0.f};

#pragma unroll
    for (int kk = 0; kk < 4; ++kk) {
        const int kb = kk * 32 + lk * 8;
        bf16x8 a[2];
#pragma unroll
        for (int rg = 0; rg < 2; ++rg) {
            int row = n0 + rg * 16 + l15;
            row = row < N_NODES ? row : N_NODES - 1;
            const float4* p = (const float4*)(x + (size_t)row * 128 + kb);
            float4 f0 = p[0], f1 = p[1];
            union { bf16x8 v; unsigned short s[8]; } ua;
            ua.s[0] = f2bf(f0.x); ua.s[1] = f2bf(f0.y);
            ua.s[2] = f2bf(f0.z); ua.s[3] = f2bf(f0.w);
            ua.s[4] = f2bf(f1.x); ua.s[5] = f2bf(f1.y);
            ua.s[6] = f2bf(f1.z); ua.s[7] = f2bf(f1.w);
            a[rg] = ua.v;
        }
#pragma unroll
        for (int t = 0; t < 6; ++t) {
            const int j0 = w * 96 + t * 16;
            bf16x8 b = *(const bf16x8*)(WT + (size_t)(j0 + l15) * 128 + kb);
            acc[t][0] = __builtin_amdgcn_mfma_f32_16x16x32_bf16(a[0], b, acc[t][0], 0, 0, 0);
            acc[t][1] = __builtin_amdgcn_mfma_f32_16x16x32_bf16(a[1], b, acc[t][1], 0, 0, 0);
        }
    }

#pragma unroll
    for (int t = 0; t < 6; ++t) {
        const int j = w * 96 + t * 16 + l15;
        const float bias = bqkv[j];
        unsigned short* O = j < 128 ? Q : j < 256 ? K : V;
        const int jj = j & 127;
#pragma unroll
        for (int rg = 0; rg < 2; ++rg)
#pragma unroll
            for (int r = 0; r < 4; ++r) {
                int row = n0 + rg * 16 + lk * 4 + r;
                if (row < N_NODES)
                    O[(size_t)row * 128 + jj] = f2bf(acc[t][rg][r] + bias);
            }
    }
}

// ---------------------------------------------------------------------------
// Kernel 2: invert edge list into per-dst buckets (src ids).
// ---------------------------------------------------------------------------
__global__ __launch_bounds__(256) void fill_kernel(
    const int* __restrict__ src, const int* __restrict__ dst,
    int* __restrict__ counts, int* __restrict__ bucket)
{
    const int e = blockIdx.x * 256 + threadIdx.x;
    if (e >= N_EDGES) return;
    const int s = src[e];
    const int d = dst[e];
    const int pos = atomicAdd(&counts[d], 1);
    if (pos < CAP) bucket[(size_t)d * CAP + pos] = s;
}

// ---------------------------------------------------------------------------
// Kernel 3: per-dst gather + weighted sum + LN1 + LN2, fused.
// 16 lanes per node; lane owns elems 8l..8l+7.  u output in bf16.
// ---------------------------------------------------------------------------
__device__ __forceinline__ void edge_accum(uint4 kw, uint4 vw,
                                           const float* q, float* acc)
{
    float kf[8];
    unpack8(kw, kf);
    float dot = q[0]*kf[0] + q[1]*kf[1] + q[2]*kf[2] + q[3]*kf[3]
              + q[4]*kf[4] + q[5]*kf[5] + q[6]*kf[6] + q[7]*kf[7];
    dot += __shfl_xor(dot, 1);          // head-wide dot (2 lanes x 8)
    float sc = dot * 0.25f;             // 1/sqrt(16)
    sc = fminf(fmaxf(sc, -5.f), 5.f);
    sc = __expf(sc);
    float vf[8];
    unpack8(vw, vf);
#pragma unroll
    for (int j = 0; j < 8; ++j) acc[j] = fmaf(vf[j], sc, acc[j]);
}

__global__ __launch_bounds__(256) void gather_ln_kernel(
    const float* __restrict__ x,
    const unsigned short* __restrict__ Qb, const unsigned short* __restrict__ Kb,
    const unsigned short* __restrict__ Vb,
    const int* __restrict__ counts, const int* __restrict__ bucket,
    const float* __restrict__ g1, const float* __restrict__ b1,
    const float* __restrict__ g2, const float* __restrict__ b2,
    float* __restrict__ h, unsigned short* __restrict__ u)
{
    const int gid  = blockIdx.x * 256 + threadIdx.x;
    const int node = gid >> 4;
    if (node >= N_NODES) return;
    const int lane = threadIdx.x & 15;   // 16-lane group

    const uint4* Q4 = (const uint4*)Qb;
    const uint4* K4 = (const uint4*)Kb;
    const uint4* V4 = (const uint4*)Vb;

    float q[8];
    unpack8(Q4[(size_t)node * 16 + lane], q);

    int cnt = counts[node];
    if (cnt > CAP) cnt = CAP;
    const size_t base = (size_t)node * CAP;

    float acc[8];
#pragma unroll
    for (int j = 0; j < 8; ++j) acc[j] = 0.f;

    int i = 0;
    for (; i + 2 <= cnt; i += 2) {
        const int s0 = bucket[base + i];
        const int s1 = bucket[base + i + 1];
        const uint4 kw0 = K4[(size_t)s0 * 16 + lane];
        const uint4 vw0 = V4[(size_t)s0 * 16 + lane];
        const uint4 kw1 = K4[(size_t)s1 * 16 + lane];
        const uint4 vw1 = V4[(size_t)s1 * 16 + lane];
        edge_accum(kw0, vw0, q, acc);
        edge_accum(kw1, vw1, q, acc);
    }
    if (i < cnt) {
        const int s0 = bucket[base + i];
        const uint4 kw0 = K4[(size_t)s0 * 16 + lane];
        const uint4 vw0 = V4[(size_t)s0 * 16 + lane];
        edge_accum(kw0, vw0, q, acc);
    }

    // a = x + wV
    const float4* x4 = (const float4*)(x + (size_t)node * DIM);
    float4 xa = x4[lane * 2], xb = x4[lane * 2 + 1];
    float a[8] = { xa.x + acc[0], xa.y + acc[1], xa.z + acc[2], xa.w + acc[3],
                   xb.x + acc[4], xb.y + acc[5], xb.z + acc[6], xb.w + acc[7] };

    // ---- LN1 across 16-lane group (128 elems) ----
    float sum = 0.f;
#pragma unroll
    for (int j = 0; j < 8; ++j) sum += a[j];
#pragma unroll
    for (int m = 1; m < 16; m <<= 1) sum += __shfl_xor(sum, m);
    float mean = sum * (1.f / 128.f);
    float vs = 0.f;
#pragma unroll
    for (int j = 0; j < 8; ++j) { a[j] -= mean; vs += a[j] * a[j]; }
#pragma unroll
    for (int m = 1; m < 16; m <<= 1) vs += __shfl_xor(vs, m);
    float rstd = rsqrtf(vs * (1.f / 128.f) + 1e-5f);

    const float4 g1a = ((const float4*)g1)[lane * 2], g1b = ((const float4*)g1)[lane * 2 + 1];
    const float4 b1a = ((const float4*)b1)[lane * 2], b1b = ((const float4*)b1)[lane * 2 + 1];
    float hv[8];
    hv[0] = a[0] * rstd * g1a.x + b1a.x;  hv[1] = a[1] * rstd * g1a.y + b1a.y;
    hv[2] = a[2] * rstd * g1a.z + b1a.z;  hv[3] = a[3] * rstd * g1a.w + b1a.w;
    hv[4] = a[4] * rstd * g1b.x + b1b.x;  hv[5] = a[5] * rstd * g1b.y + b1b.y;
    hv[6] = a[6] * rstd * g1b.z + b1b.z;  hv[7] = a[7] * rstd * g1b.w + b1b.w;

    float4* h4 = (float4*)(h + (size_t)node * DIM);
    h4[lane * 2]     = make_float4(hv[0], hv[1], hv[2], hv[3]);
    h4[lane * 2 + 1] = make_float4(hv[4], hv[5], hv[6], hv[7]);

    // ---- LN2 over h ----
    float sum2 = 0.f;
#pragma unroll
    for (int j = 0; j < 8; ++j) sum2 += hv[j];
#pragma unroll
    for (int m = 1; m < 16; m <<= 1) sum2 += __shfl_xor(sum2, m);
    float mean2 = sum2 * (1.f / 128.f);
    float vs2 = 0.f;
#pragma unroll
    for (int j = 0; j < 8; ++j) { hv[j] -= mean2; vs2 += hv[j] * hv[j]; }
#pragma unroll
    for (int m = 1; m < 16; m <<= 1) vs2 += __shfl_xor(vs2, m);
    float rstd2 = rsqrtf(vs2 * (1.f / 128.f) + 1e-5f);

    const float4 g2a = ((const float4*)g2)[lane * 2], g2b = ((const float4*)g2)[lane * 2 + 1];
    const float4 b2a = ((const float4*)b2)[lane * 2], b2b = ((const float4*)b2)[lane * 2 + 1];
    float uv[8];
    uv[0] = hv[0] * rstd2 * g2a.x + b2a.x;  uv[1] = hv[1] * rstd2 * g2a.y + b2a.y;
    uv[2] = hv[2] * rstd2 * g2a.z + b2a.z;  uv[3] = hv[3] * rstd2 * g2a.w + b2a.w;
    uv[4] = hv[4] * rstd2 * g2b.x + b2b.x;  uv[5] = hv[5] * rstd2 * g2b.y + b2b.y;
    uv[6] = hv[6] * rstd2 * g2b.z + b2b.z;  uv[7] = hv[7] * rstd2 * g2b.w + b2b.w;

    uint4 up;
    up.x = (unsigned)f2bf(uv[0]) | ((unsigned)f2bf(uv[1]) << 16);
    up.y = (unsigned)f2bf(uv[2]) | ((unsigned)f2bf(uv[3]) << 16);
    up.z = (unsigned)f2bf(uv[4]) | ((unsigned)f2bf(uv[5]) << 16);
    up.w = (unsigned)f2bf(uv[6]) | ((unsigned)f2bf(uv[7]) << 16);
    ((uint4*)(u + (size_t)node * DIM))[lane] = up;
}

// ---------------------------------------------------------------------------
// Kernel 4: out = h + relu(u @ Wo + bo) via MFMA.  Block = 4 waves, 32 rows;
// wave w computes cols [32w, 32w+32).
// ---------------------------------------------------------------------------
__global__ __launch_bounds__(256) void out_mfma(
    const unsigned short* __restrict__ u, const unsigned short* __restrict__ WoT,
    const float* __restrict__ bo, float* __restrict__ out /* holds h */)
{
    const int w   = threadIdx.x >> 6;
    const int l   = threadIdx.x & 63;
    const int l15 = l & 15;
    const int lk  = l >> 4;
    const int n0  = blockIdx.x * 32;

    f32x4 acc[2][2];
#pragma unroll
    for (int t = 0; t < 2; ++t)
#pragma unroll
        for (int rg = 0; rg < 2; ++rg) acc[t][rg] = (f32x4){0.f, 0.f, 0.f, 0.f};

#pragma unroll
    for (int kk = 0; kk < 4; ++kk) {
        const int kb = kk * 32 + lk * 8;
        bf16x8 a[2];
#pragma unroll
        for (int rg = 0; rg < 2; ++rg) {
            int row = n0 + rg * 16 + l15;
            row = row < N_NODES ? row : N_NODES - 1;
            a[rg] = *(const bf16x8*)(u + (size_t)row * 128 + kb);
        }
#pragma unroll
        for (int t = 0; t < 2; ++t) {
            const int j0 = w * 32 + t * 16;
            bf16x8 b = *(const bf16x8*)(WoT + (size_t)(j0 + l15) * 128 + kb);
            acc[t][0] = __builtin_amdgcn_mfma_f32_16x16x32_bf16(a[0], b, acc[t][0], 0, 0, 0);
            acc[t][1] = __builtin_amdgcn_mfma_f32_16x16x32_bf16(a[1], b, acc[t][1], 0, 0, 0);
        }
    }

#pragma unroll
    for (int t = 0; t < 2; ++t) {
        const int j = w * 32 + t * 16 + l15;
        const float bias = bo[j];
#pragma unroll
        for (int rg = 0; rg < 2; ++rg)
#pragma unroll
            for (int r = 0; r < 4; ++r) {
                int row = n0 + rg * 16 + lk * 4 + r;
                if (row < N_NODES) {
                    size_t o = (size_t)row * 128 + j;
                    out[o] = out[o] + fmaxf(acc[t][rg][r] + bias, 0.f);
                }
            }
    }
}

// ---------------------------------------------------------------------------
extern "C" void kernel_launch(void* const* d_in, const int* in_sizes, int n_in,
                              void* d_out, int out_size, void* d_ws, size_t ws_size,
                              hipStream_t stream)
{
    const float* x    = (const float*)d_in[0];
    const int*   src  = (const int*)  d_in[1];
    const int*   dst  = (const int*)  d_in[2];
    const float* Wq   = (const float*)d_in[3];
    const float* bq   = (const float*)d_in[4];
    const float* Wk   = (const float*)d_in[5];
    const float* bk   = (const float*)d_in[6];
    const float* Wv   = (const float*)d_in[7];
    const float* bv   = (const float*)d_in[8];
    const float* Wo   = (const float*)d_in[9];
    const float* bo   = (const float*)d_in[10];
    const float* ln1g = (const float*)d_in[11];
    const float* ln1b = (const float*)d_in[12];
    const float* ln2g = (const float*)d_in[13];
    const float* ln2b = (const float*)d_in[14];

    float* out = (float*)d_out;              // holds h, then final output
    char*  wsb = (char*)d_ws;

    const size_t NM = (size_t)N_NODES * DIM; // 6.4M elems
    unsigned short* Qb = (unsigned short*)(wsb);
    unsigned short* Kb = Qb + NM;
    unsigned short* Vb = Kb + NM;
    unsigned short* u  = Vb + NM;
    unsigned short* WT  = u + NM;            // 384*128
    unsigned short* WoT = WT + 384 * 128;    // 128*128
    float* bqkv   = (float*)(WoT + 128 * 128);
    int*   counts = (int*)(bqkv + 384);
    int*   bucket = counts + N_NODES;        // 19.2 MB

    hipMemsetAsync(counts, 0, N_NODES * sizeof(int), stream);

    prep_kernel<<<(384 * 128 + 128 * 128 + 384 + 255) / 256, 256, 0, stream>>>(
        Wq, Wk, Wv, Wo, bq, bk, bv, WT, WoT, bqkv);

    qkv_mfma<<<(N_NODES + 31) / 32, 256, 0, stream>>>(
        x, WT, bqkv, Qb, Kb, Vb);

    fill_kernel<<<(N_EDGES + 255) / 256, 256, 0, stream>>>(
        src, dst, counts, bucket);

    gather_ln_kernel<<<(N_NODES * 16 + 255) / 256, 256, 0, stream>>>(
        x, Qb, Kb, Vb, counts, bucket, ln1g, ln1b, ln2g, ln2b, out, u);

    out_mfma<<<(N_NODES + 31) / 32, 256, 0, stream>>>(u, WoT, bo, out);
}

// Round 5
// 178.986 us; speedup vs baseline: 8.5867x; 1.1225x over previous
//
#include <hip/hip_runtime.h>
#include <hip/hip_bf16.h>

#define N_NODES 50000
#define N_EDGES 800000
#define DIM     128
#define CAP     96          // per-dst bucket capacity (max degree ~44 for Poisson(16))

typedef __attribute__((ext_vector_type(8))) short bf16x8;
typedef __attribute__((ext_vector_type(4))) float f32x4;

// ---------------------------------------------------------------------------
// bf16 helpers
// ---------------------------------------------------------------------------
__device__ __forceinline__ unsigned short f2bf(float f) {   // RNE
    union { float f; unsigned u; } c; c.f = f;
    unsigned r = c.u + 0x7fffu + ((c.u >> 16) & 1u);
    return (unsigned short)(r >> 16);
}
__device__ __forceinline__ float bfhi(unsigned int u) {
    union { unsigned int u; float f; } c; c.u = u & 0xffff0000u; return c.f;
}
__device__ __forceinline__ float bflo(unsigned int u) {
    union { unsigned int u; float f; } c; c.u = u << 16; return c.f;
}
__device__ __forceinline__ void unpack8(uint4 w, float* f) {
    f[0] = bflo(w.x); f[1] = bfhi(w.x);
    f[2] = bflo(w.y); f[3] = bfhi(w.y);
    f[4] = bflo(w.z); f[5] = bfhi(w.z);
    f[6] = bflo(w.w); f[7] = bfhi(w.w);
}

// ---------------------------------------------------------------------------
// Kernel 0: transpose weights to [n][k] bf16, concat qkv bias.
// ---------------------------------------------------------------------------
__global__ __launch_bounds__(256) void prep_kernel(
    const float* __restrict__ Wq, const float* __restrict__ Wk,
    const float* __restrict__ Wv, const float* __restrict__ Wo,
    const float* __restrict__ bq, const float* __restrict__ bk,
    const float* __restrict__ bv,
    unsigned short* __restrict__ WT, unsigned short* __restrict__ WoT,
    float* __restrict__ bqkv)
{
    const int t = blockIdx.x * 256 + threadIdx.x;
    if (t < 384 * 128) {
        int j = t >> 7, k = t & 127;
        int which = j >> 7, jj = j & 127;
        const float* W = which == 0 ? Wq : which == 1 ? Wk : Wv;
        WT[t] = f2bf(W[k * 128 + jj]);
    } else if (t < 384 * 128 + 128 * 128) {
        int t2 = t - 384 * 128;
        int j = t2 >> 7, k = t2 & 127;
        WoT[t2] = f2bf(Wo[k * 128 + j]);
    } else if (t < 384 * 128 + 128 * 128 + 384) {
        int j = t - (384 * 128 + 128 * 128);
        bqkv[j] = j < 128 ? bq[j] : j < 256 ? bk[j - 128] : bv[j - 256];
    }
}

// ---------------------------------------------------------------------------
// Kernel 1: QKV projection via MFMA, C staged through LDS for coalesced
// bf16 stores.  Block = 4 waves, 32 rows; wave w owns cols [96w, 96w+96).
// ---------------------------------------------------------------------------
__global__ __launch_bounds__(256) void qkv_mfma(
    const float* __restrict__ x, const unsigned short* __restrict__ WT,
    const float* __restrict__ bqkv,
    unsigned short* __restrict__ Q, unsigned short* __restrict__ K,
    unsigned short* __restrict__ V)
{
    __shared__ unsigned short cs[32][384];

    const int w   = threadIdx.x >> 6;
    const int l   = threadIdx.x & 63;
    const int l15 = l & 15;
    const int lk  = l >> 4;
    const int n0  = blockIdx.x * 32;

    f32x4 acc[6][2];
#pragma unroll
    for (int t = 0; t < 6; ++t)
#pragma unroll
        for (int rg = 0; rg < 2; ++rg) acc[t][rg] = (f32x4){0.f, 0.f, 0.f, 0.f};

#pragma unroll
    for (int kk = 0; kk < 4; ++kk) {
        const int kb = kk * 32 + lk * 8;
        bf16x8 a[2];
#pragma unroll
        for (int rg = 0; rg < 2; ++rg) {
            int row = n0 + rg * 16 + l15;
            row = row < N_NODES ? row : N_NODES - 1;
            const float4* p = (const float4*)(x + (size_t)row * 128 + kb);
            float4 f0 = p[0], f1 = p[1];
            union { bf16x8 v; unsigned short s[8]; } ua;
            ua.s[0] = f2bf(f0.x); ua.s[1] = f2bf(f0.y);
            ua.s[2] = f2bf(f0.z); ua.s[3] = f2bf(f0.w);
            ua.s[4] = f2bf(f1.x); ua.s[5] = f2bf(f1.y);
            ua.s[6] = f2bf(f1.z); ua.s[7] = f2bf(f1.w);
            a[rg] = ua.v;
        }
#pragma unroll
        for (int t = 0; t < 6; ++t) {
            const int j0 = w * 96 + t * 16;
            bf16x8 b = *(const bf16x8*)(WT + (size_t)(j0 + l15) * 128 + kb);
            acc[t][0] = __builtin_amdgcn_mfma_f32_16x16x32_bf16(a[0], b, acc[t][0], 0, 0, 0);
            acc[t][1] = __builtin_amdgcn_mfma_f32_16x16x32_bf16(a[1], b, acc[t][1], 0, 0, 0);
        }
    }

    // stage C (bias added, bf16) into LDS
#pragma unroll
    for (int t = 0; t < 6; ++t) {
        const int j = w * 96 + t * 16 + l15;
        const float bias = bqkv[j];
#pragma unroll
        for (int rg = 0; rg < 2; ++rg)
#pragma unroll
            for (int r = 0; r < 4; ++r)
                cs[rg * 16 + lk * 4 + r][j] = f2bf(acc[t][rg][r] + bias);
    }
    __syncthreads();

    // coalesced uint4 stores: 32 rows x 48 uint4 (8 bf16 each)
    for (int idx = threadIdx.x; idx < 32 * 48; idx += 256) {
        const int row = idx / 48, c16 = idx % 48;
        const int node = n0 + row;
        if (node < N_NODES) {
            uint4 val = ((const uint4*)cs[row])[c16];
            const int c = c16 * 8;
            unsigned short* O = c < 128 ? Q : c < 256 ? K : V;
            *(uint4*)(O + (size_t)node * 128 + (c & 127)) = val;
        }
    }
}

// ---------------------------------------------------------------------------
// Kernel 2: invert edge list into per-dst buckets (src ids).
// ---------------------------------------------------------------------------
__global__ __launch_bounds__(256) void fill_kernel(
    const int* __restrict__ src, const int* __restrict__ dst,
    int* __restrict__ counts, int* __restrict__ bucket)
{
    const int e = blockIdx.x * 256 + threadIdx.x;
    if (e >= N_EDGES) return;
    const int s = src[e];
    const int d = dst[e];
    const int pos = atomicAdd(&counts[d], 1);
    if (pos < CAP) bucket[(size_t)d * CAP + pos] = s;
}

// ---------------------------------------------------------------------------
// Kernel 3: per-dst gather + weighted sum + LN1 + LN2, fused.
// 16 lanes per node; lane owns elems 8l..8l+7.  src ids prefetched via
// coalesced lane-load + shfl broadcast; edge loop unrolled x4 (8 row loads
// in flight per group).
// ---------------------------------------------------------------------------
__device__ __forceinline__ void edge_accum(uint4 kw, uint4 vw,
                                           const float* q, float* acc)
{
    float kf[8];
    unpack8(kw, kf);
    float dot = q[0]*kf[0] + q[1]*kf[1] + q[2]*kf[2] + q[3]*kf[3]
              + q[4]*kf[4] + q[5]*kf[5] + q[6]*kf[6] + q[7]*kf[7];
    dot += __shfl_xor(dot, 1);          // head-wide dot (2 lanes x 8)
    float sc = dot * 0.25f;             // 1/sqrt(16)
    sc = fminf(fmaxf(sc, -5.f), 5.f);
    sc = __expf(sc);
    float vf[8];
    unpack8(vw, vf);
#pragma unroll
    for (int j = 0; j < 8; ++j) acc[j] = fmaf(vf[j], sc, acc[j]);
}

#define GETID(i) ((i) < 16 ? __shfl(id0, (i), 16)        \
                : (i) < 32 ? __shfl(id1, (i) - 16, 16)   \
                : (i) < 48 ? __shfl(id2, (i) - 32, 16)   \
                : bucket[base + (i)])

__global__ __launch_bounds__(256) void gather_ln_kernel(
    const float* __restrict__ x,
    const unsigned short* __restrict__ Qb, const unsigned short* __restrict__ Kb,
    const unsigned short* __restrict__ Vb,
    const int* __restrict__ counts, const int* __restrict__ bucket,
    const float* __restrict__ g1, const float* __restrict__ b1,
    const float* __restrict__ g2, const float* __restrict__ b2,
    float* __restrict__ h, unsigned short* __restrict__ u)
{
    const int gid  = blockIdx.x * 256 + threadIdx.x;
    const int node = gid >> 4;
    if (node >= N_NODES) return;
    const int lane = threadIdx.x & 15;   // 16-lane group

    const uint4* Q4 = (const uint4*)Qb;
    const uint4* K4 = (const uint4*)Kb;
    const uint4* V4 = (const uint4*)Vb;

    // early loads: residual x and Q fragment
    const float4* x4 = (const float4*)(x + (size_t)node * DIM);
    const float4 xa = x4[lane * 2], xb = x4[lane * 2 + 1];

    float q[8];
    unpack8(Q4[(size_t)node * 16 + lane], q);

    int cnt = counts[node];
    if (cnt > CAP) cnt = CAP;
    const size_t base = (size_t)node * CAP;

    // prefetch up to 48 src ids (coalesced; garbage beyond cnt is never used)
    const int id0 = bucket[base + lane];
    const int id1 = (cnt > 16) ? bucket[base + 16 + lane] : 0;
    const int id2 = (cnt > 32) ? bucket[base + 32 + lane] : 0;

    float acc[8];
#pragma unroll
    for (int j = 0; j < 8; ++j) acc[j] = 0.f;

    int i = 0;
    for (; i + 4 <= cnt; i += 4) {
        const int s0 = GETID(i), s1 = GETID(i + 1);
        const int s2 = GETID(i + 2), s3 = GETID(i + 3);
        const uint4 kw0 = K4[(size_t)s0 * 16 + lane], vw0 = V4[(size_t)s0 * 16 + lane];
        const uint4 kw1 = K4[(size_t)s1 * 16 + lane], vw1 = V4[(size_t)s1 * 16 + lane];
        const uint4 kw2 = K4[(size_t)s2 * 16 + lane], vw2 = V4[(size_t)s2 * 16 + lane];
        const uint4 kw3 = K4[(size_t)s3 * 16 + lane], vw3 = V4[(size_t)s3 * 16 + lane];
        edge_accum(kw0, vw0, q, acc);
        edge_accum(kw1, vw1, q, acc);
        edge_accum(kw2, vw2, q, acc);
        edge_accum(kw3, vw3, q, acc);
    }
    for (; i < cnt; ++i) {
        const int s0 = GETID(i);
        const uint4 kw0 = K4[(size_t)s0 * 16 + lane], vw0 = V4[(size_t)s0 * 16 + lane];
        edge_accum(kw0, vw0, q, acc);
    }

    // a = x + wV
    float a[8] = { xa.x + acc[0], xa.y + acc[1], xa.z + acc[2], xa.w + acc[3],
                   xb.x + acc[4], xb.y + acc[5], xb.z + acc[6], xb.w + acc[7] };

    // ---- LN1 across 16-lane group (128 elems) ----
    float sum = 0.f;
#pragma unroll
    for (int j = 0; j < 8; ++j) sum += a[j];
#pragma unroll
    for (int m = 1; m < 16; m <<= 1) sum += __shfl_xor(sum, m);
    float mean = sum * (1.f / 128.f);
    float vs = 0.f;
#pragma unroll
    for (int j = 0; j < 8; ++j) { a[j] -= mean; vs += a[j] * a[j]; }
#pragma unroll
    for (int m = 1; m < 16; m <<= 1) vs += __shfl_xor(vs, m);
    float rstd = rsqrtf(vs * (1.f / 128.f) + 1e-5f);

    const float4 g1a = ((const float4*)g1)[lane * 2], g1b = ((const float4*)g1)[lane * 2 + 1];
    const float4 b1a = ((const float4*)b1)[lane * 2], b1b = ((const float4*)b1)[lane * 2 + 1];
    float hv[8];
    hv[0] = a[0] * rstd * g1a.x + b1a.x;  hv[1] = a[1] * rstd * g1a.y + b1a.y;
    hv[2] = a[2] * rstd * g1a.z + b1a.z;  hv[3] = a[3] * rstd * g1a.w + b1a.w;
    hv[4] = a[4] * rstd * g1b.x + b1b.x;  hv[5] = a[5] * rstd * g1b.y + b1b.y;
    hv[6] = a[6] * rstd * g1b.z + b1b.z;  hv[7] = a[7] * rstd * g1b.w + b1b.w;

    float4* h4 = (float4*)(h + (size_t)node * DIM);
    h4[lane * 2]     = make_float4(hv[0], hv[1], hv[2], hv[3]);
    h4[lane * 2 + 1] = make_float4(hv[4], hv[5], hv[6], hv[7]);

    // ---- LN2 over h ----
    float sum2 = 0.f;
#pragma unroll
    for (int j = 0; j < 8; ++j) sum2 += hv[j];
#pragma unroll
    for (int m = 1; m < 16; m <<= 1) sum2 += __shfl_xor(sum2, m);
    float mean2 = sum2 * (1.f / 128.f);
    float vs2 = 0.f;
#pragma unroll
    for (int j = 0; j < 8; ++j) { hv[j] -= mean2; vs2 += hv[j] * hv[j]; }
#pragma unroll
    for (int m = 1; m < 16; m <<= 1) vs2 += __shfl_xor(vs2, m);
    float rstd2 = rsqrtf(vs2 * (1.f / 128.f) + 1e-5f);

    const float4 g2a = ((const float4*)g2)[lane * 2], g2b = ((const float4*)g2)[lane * 2 + 1];
    const float4 b2a = ((const float4*)b2)[lane * 2], b2b = ((const float4*)b2)[lane * 2 + 1];
    float uv[8];
    uv[0] = hv[0] * rstd2 * g2a.x + b2a.x;  uv[1] = hv[1] * rstd2 * g2a.y + b2a.y;
    uv[2] = hv[2] * rstd2 * g2a.z + b2a.z;  uv[3] = hv[3] * rstd2 * g2a.w + b2a.w;
    uv[4] = hv[4] * rstd2 * g2b.x + b2b.x;  uv[5] = hv[5] * rstd2 * g2b.y + b2b.y;
    uv[6] = hv[6] * rstd2 * g2b.z + b2b.z;  uv[7] = hv[7] * rstd2 * g2b.w + b2b.w;

    uint4 up;
    up.x = (unsigned)f2bf(uv[0]) | ((unsigned)f2bf(uv[1]) << 16);
    up.y = (unsigned)f2bf(uv[2]) | ((unsigned)f2bf(uv[3]) << 16);
    up.z = (unsigned)f2bf(uv[4]) | ((unsigned)f2bf(uv[5]) << 16);
    up.w = (unsigned)f2bf(uv[6]) | ((unsigned)f2bf(uv[7]) << 16);
    ((uint4*)(u + (size_t)node * DIM))[lane] = up;
}

// ---------------------------------------------------------------------------
// Kernel 4: out = h + relu(u @ Wo + bo) via MFMA, LDS-staged coalesced RMW.
// ---------------------------------------------------------------------------
__global__ __launch_bounds__(256) void out_mfma(
    const unsigned short* __restrict__ u, const unsigned short* __restrict__ WoT,
    const float* __restrict__ bo, float* __restrict__ out /* holds h */)
{
    __shared__ float ls[32][128];

    const int w   = threadIdx.x >> 6;
    const int l   = threadIdx.x & 63;
    const int l15 = l & 15;
    const int lk  = l >> 4;
    const int n0  = blockIdx.x * 32;

    f32x4 acc[2][2];
#pragma unroll
    for (int t = 0; t < 2; ++t)
#pragma unroll
        for (int rg = 0; rg < 2; ++rg) acc[t][rg] = (f32x4){0.f, 0.f, 0.f, 0.f};

#pragma unroll
    for (int kk = 0; kk < 4; ++kk) {
        const int kb = kk * 32 + lk * 8;
        bf16x8 a[2];
#pragma unroll
        for (int rg = 0; rg < 2; ++rg) {
            int row = n0 + rg * 16 + l15;
            row = row < N_NODES ? row : N_NODES - 1;
            a[rg] = *(const bf16x8*)(u + (size_t)row * 128 + kb);
        }
#pragma unroll
        for (int t = 0; t < 2; ++t) {
            const int j0 = w * 32 + t * 16;
            bf16x8 b = *(const bf16x8*)(WoT + (size_t)(j0 + l15) * 128 + kb);
            acc[t][0] = __builtin_amdgcn_mfma_f32_16x16x32_bf16(a[0], b, acc[t][0], 0, 0, 0);
            acc[t][1] = __builtin_amdgcn_mfma_f32_16x16x32_bf16(a[1], b, acc[t][1], 0, 0, 0);
        }
    }

#pragma unroll
    for (int t = 0; t < 2; ++t) {
        const int j = w * 32 + t * 16 + l15;
        const float bias = bo[j];
#pragma unroll
        for (int rg = 0; rg < 2; ++rg)
#pragma unroll
            for (int r = 0; r < 4; ++r)
                ls[rg * 16 + lk * 4 + r][j] = fmaxf(acc[t][rg][r] + bias, 0.f);
    }
    __syncthreads();

    for (int idx = threadIdx.x; idx < 32 * 32; idx += 256) {
        const int row = idx / 32, c4 = idx % 32;
        const int node = n0 + row;
        if (node < N_NODES) {
            float4 v = ((const float4*)ls[row])[c4];
            float4* po = (float4*)(out + (size_t)node * 128) + c4;
            float4 hv = *po;
            *po = make_float4(hv.x + v.x, hv.y + v.y, hv.z + v.z, hv.w + v.w);
        }
    }
}

// ---------------------------------------------------------------------------
extern "C" void kernel_launch(void* const* d_in, const int* in_sizes, int n_in,
                              void* d_out, int out_size, void* d_ws, size_t ws_size,
                              hipStream_t stream)
{
    const float* x    = (const float*)d_in[0];
    const int*   src  = (const int*)  d_in[1];
    const int*   dst  = (const int*)  d_in[2];
    const float* Wq   = (const float*)d_in[3];
    const float* bq   = (const float*)d_in[4];
    const float* Wk   = (const float*)d_in[5];
    const float* bk   = (const float*)d_in[6];
    const float* Wv   = (const float*)d_in[7];
    const float* bv   = (const float*)d_in[8];
    const float* Wo   = (const float*)d_in[9];
    const float* bo   = (const float*)d_in[10];
    const float* ln1g = (const float*)d_in[11];
    const float* ln1b = (const float*)d_in[12];
    const float* ln2g = (const float*)d_in[13];
    const float* ln2b = (const float*)d_in[14];

    float* out = (float*)d_out;              // holds h, then final output
    char*  wsb = (char*)d_ws;

    const size_t NM = (size_t)N_NODES * DIM; // 6.4M elems
    unsigned short* Qb = (unsigned short*)(wsb);
    unsigned short* Kb = Qb + NM;
    unsigned short* Vb = Kb + NM;
    unsigned short* u  = Vb + NM;
    unsigned short* WT  = u + NM;            // 384*128
    unsigned short* WoT = WT + 384 * 128;    // 128*128
    float* bqkv   = (float*)(WoT + 128 * 128);
    int*   counts = (int*)(bqkv + 384);
    int*   bucket = counts + N_NODES;        // 19.2 MB

    hipMemsetAsync(counts, 0, N_NODES * sizeof(int), stream);

    prep_kernel<<<(384 * 128 + 128 * 128 + 384 + 255) / 256, 256, 0, stream>>>(
        Wq, Wk, Wv, Wo, bq, bk, bv, WT, WoT, bqkv);

    qkv_mfma<<<(N_NODES + 31) / 32, 256, 0, stream>>>(
        x, WT, bqkv, Qb, Kb, Vb);

    fill_kernel<<<(N_EDGES + 255) / 256, 256, 0, stream>>>(
        src, dst, counts, bucket);

    gather_ln_kernel<<<(N_NODES * 16 + 255) / 256, 256, 0, stream>>>(
        x, Qb, Kb, Vb, counts, bucket, ln1g, ln1b, ln2g, ln2b, out, u);

    out_mfma<<<(N_NODES + 31) / 32, 256, 0, stream>>>(u, WoT, bo, out);
}